// Round 5
// baseline (23112.163 us; speedup 1.0000x reference)
//
#include <hip/hip_runtime.h>
#include <math.h>

// ESN forward: x_{t+1} = 0.1*x_t + 0.9*tanh(W_in @ u_t + W @ x_t); y_t = Wout @ x_{t+1}
// R9 = R6's proven exchange skeleton (hint flag + ONE validated epoch-in-data
// round, fence-free, entries streamed from L2 in-loop) scaled to 128 WGs:
//  - 32 rows/WG, 16 threads/row -> per-CU gather pipe time and per-thread
//    serial FMA chain both halve; 128 of 256 CUs active.
//  - variable-length round-robin gather (numerics proven in R7): lane ln of a
//    16-thread group reads int4s {ln, ln+16, ...}, nit = ceil(rlen/32),
//    avg ~7 int4s vs 11 fixed; perfectly coalesced L2 stream.
//  - exchange unchanged per thread: 8 staged words = one 64B line from ONE
//    producer WG (pf = tid>>2); flag is a hint, data epochs are the gate.
//  - WGs 0..63 own Y rows; WGs 64..127 skip the (off-path) readout.
//  - kernel 1 zeroes xbuf + flags (stale-epoch insurance across launches).
// R8 lesson: ELL-in-LDS hurts (bank aliasing + LDS pipe contention); L2 is
// the right home for entries. R7 lesson: never drop the hint flag.

#define NX 4096
#define NU 128
#define NY 64
#define TSTEPS 4096
#define CAP 352            // storage pad (mean nnz 204.8, sd 13.9; +10.6 sd)
#define WGS 128
#define TPB 512
#define RPW (NX / WGS)     // 32 rows per workgroup
#define TPR (TPB / RPW)    // 16 threads per row
#define UPT (NU / TPR)     // 8 W_in floats per thread
#define WPT (NX / TPB)     // 8 exchange words / readout floats per thread

typedef unsigned long long u64;
typedef unsigned int u32;

// --- Kernel 1: deterministic dense->ELL compaction + row lengths; zero xbuf/flags ---
__global__ void build_ell_kernel(const float* __restrict__ W, int2* __restrict__ ell,
                                 int* __restrict__ rlen, u64* __restrict__ xbuf,
                                 u32* __restrict__ flags) {
    const int r = blockIdx.x;
    const int tid = threadIdx.x;
    if (r == 0 && tid < WGS) flags[tid] = 0;         // re-zero every launch
    if (r < 32) xbuf[r * 256 + tid] = 0;             // 32*256 = 8192 words
    const int wv = tid >> 6, ln = tid & 63;
    __shared__ int wave_tot[4];
    __shared__ int base;
    if (tid == 0) base = 0;
    __syncthreads();
    const float* row = W + (size_t)r * NX;
    int2* out = ell + (size_t)r * CAP;
    for (int chunk = 0; chunk < NX; chunk += 256) {
        float w = row[chunk + tid];
        bool p = (w != 0.0f);
        unsigned long long m = __ballot(p);
        int lp = (int)__popcll(m & ((1ull << ln) - 1ull));
        if (ln == 63) wave_tot[wv] = lp + (p ? 1 : 0);
        __syncthreads();
        int wbase = 0;
        #pragma unroll
        for (int i = 0; i < 4; ++i)
            if (i < wv) wbase += wave_tot[i];
        int tot = wave_tot[0] + wave_tot[1] + wave_tot[2] + wave_tot[3];
        if (p) {
            int o = base + wbase + lp;
            if (o < CAP) out[o] = make_int2(chunk + tid, __float_as_int(w));
        }
        __syncthreads();
        if (tid == 0) base += tot;
        __syncthreads();
    }
    // zero-pad remainder: col=0, val=0 contributes exactly 0
    for (int o = base + tid; o < CAP; o += 256) out[o] = make_int2(0, 0);
    if (tid == 0) rlen[r] = (base < CAP) ? base : CAP;
}

// --- Kernel 2: cooperative sequential recurrence (R6 exchange, 128 WGs) ---
__global__ void __launch_bounds__(TPB, 1) esn_kernel(
    const float* __restrict__ UT, const float* __restrict__ x0,
    const float* __restrict__ Win, const float* __restrict__ Wout,
    const int2* __restrict__ ell, const int* __restrict__ rlen,
    u64* __restrict__ xbuf,   // [2][NX] packed (epoch<<32 | float bits)
    u32* __restrict__ flags,  // [WGS] hint only (data epochs are the gate)
    float* __restrict__ Y)
{
    __shared__ __align__(16) float xl[2][NX];
    __shared__ float red[TPB / 64];

    const int tid = threadIdx.x;
    const int wg  = blockIdx.x;              // 0..127
    const int grp = tid >> 4;                // row group within WG (0..31)
    const int ln  = tid & 15;                // lane within row group
    const int r   = wg * RPW + grp;          // global row this 16-thread group owns
    const int pf  = tid >> 2;                // producer WG of this thread's 8 words

    // round-robin ELL view: lane ln consumes int4 indices {ln, ln+16, ln+32, ...}
    const int4* e4  = (const int4*)(ell + (size_t)r * CAP) + ln;
    const int   nit = (rlen[r] + 31) >> 5;   // int4s per lane (zero-padded)

    float4 wreg_in[UPT / 4];                 // Win[r, ln*8 .. +8) pinned
    {
        const float4* winrow = (const float4*)(Win + (size_t)r * NU + ln * UPT);
        #pragma unroll
        for (int i = 0; i < UPT / 4; ++i) wreg_in[i] = winrow[i];
    }
    float wreg_out[WPT];                     // Wout[wg, tid::512] (only wg < NY)
    if (wg < NY) {
        const float* woutrow = Wout + (size_t)wg * NX;
        #pragma unroll
        for (int i = 0; i < WPT; ++i) wreg_out[i] = woutrow[tid + i * TPB];
    }

    for (int t = 0; t < TSTEPS; ++t) {
        float* xc = xl[t & 1];

        // ---- x-independent partial: acc = Win[r,:] @ u_t (before spin) ----
        float acc = 0.0f;
        {
            const float4* u4 = (const float4*)(UT + (size_t)t * NU + ln * UPT);
            #pragma unroll
            for (int i = 0; i < UPT / 4; ++i) {
                float4 u = u4[i];
                acc += wreg_in[i].x * u.x + wreg_in[i].y * u.y
                     + wreg_in[i].z * u.z + wreg_in[i].w * u.w;
            }
        }

        // ---- stage x_t into LDS (R6 exchange, verbatim) ----
        if (t == 0) {
            const float4* xs4 = (const float4*)x0;
            float4* dst = (float4*)(xc + tid * WPT);
            dst[0] = xs4[2 * tid];
            dst[1] = xs4[2 * tid + 1];
        } else {
            // cheap spin: one 4B relaxed hint (no ordering semantics)
            while (__hip_atomic_load(flags + pf, __ATOMIC_RELAXED,
                                     __HIP_MEMORY_SCOPE_AGENT) < (u32)t) { }
            // validated data round: 8 packed words, one 64B line, one producer WG
            const u64* xs = xbuf + (size_t)(t & 1) * NX + (size_t)tid * WPT;
            u64 v[WPT];
            bool ok;
            do {
                ok = true;
                #pragma unroll
                for (int j = 0; j < WPT; ++j)
                    v[j] = __hip_atomic_load(xs + j, __ATOMIC_RELAXED,
                                             __HIP_MEMORY_SCOPE_AGENT);
                #pragma unroll
                for (int j = 0; j < WPT; ++j)
                    ok &= ((u32)(v[j] >> 32) == (u32)t);
            } while (!ok);
            float4 lo = make_float4(__uint_as_float((u32)v[0]), __uint_as_float((u32)v[1]),
                                    __uint_as_float((u32)v[2]), __uint_as_float((u32)v[3]));
            float4 hi = make_float4(__uint_as_float((u32)v[4]), __uint_as_float((u32)v[5]),
                                    __uint_as_float((u32)v[6]), __uint_as_float((u32)v[7]));
            float4* dst = (float4*)(xc + tid * WPT);
            dst[0] = lo;
            dst[1] = hi;
        }
        __syncthreads();

        // ---- acc += W[r,:] @ x_t (coalesced L2 entry stream, LDS x-gather) ----
        #pragma unroll 2
        for (int i = 0; i < nit; ++i) {
            int4 cv = e4[i << 4];
            acc += __int_as_float(cv.y) * xc[cv.x]
                 + __int_as_float(cv.w) * xc[cv.z];
        }
        acc += __shfl_down(acc, 8, 16);
        acc += __shfl_down(acc, 4, 16);
        acc += __shfl_down(acc, 2, 16);
        acc += __shfl_down(acc, 1, 16);

        // ---- publish x_{t+1} immediately: one packed 8B store per row ----
        if (ln == 0) {
            float xnew = 0.1f * xc[r] + 0.9f * tanhf(acc);
            u64 packed = ((u64)(u32)(t + 1) << 32) | (u64)__float_as_uint(xnew);
            __hip_atomic_store(xbuf + (size_t)((t + 1) & 1) * NX + r, packed,
                               __ATOMIC_RELAXED, __HIP_MEMORY_SCOPE_AGENT);
        }

        // ---- readout Y[t-1] = Wout[wg] . x_t (wg < NY only; off the path) ----
        if (wg < NY && t > 0) {
            float a = 0.0f;
            #pragma unroll
            for (int i = 0; i < WPT; ++i) a += wreg_out[i] * xc[tid + i * TPB];
            for (int off = 32; off; off >>= 1) a += __shfl_down(a, off, 64);
            if ((tid & 63) == 0) red[tid >> 6] = a;
        }
        __syncthreads();   // all publishes issued before this point
        if (tid == 0) {
            __hip_atomic_store(flags + wg, (u32)(t + 1),
                               __ATOMIC_RELAXED, __HIP_MEMORY_SCOPE_AGENT);
            if (wg < NY && t > 0) {
                float s = 0.0f;
                #pragma unroll
                for (int i = 0; i < TPB / 64; ++i) s += red[i];
                Y[(size_t)(t - 1) * NY + wg] = s;
            }
        }
    }

    // ---- final: only Y-owning WGs stage x_T (epoch TSTEPS) and emit Y[T-1] ----
    if (wg < NY) {
        float* xc = xl[0];
        while (__hip_atomic_load(flags + pf, __ATOMIC_RELAXED,
                                 __HIP_MEMORY_SCOPE_AGENT) < (u32)TSTEPS) { }
        const u64* xs = xbuf + (size_t)(TSTEPS & 1) * NX + (size_t)tid * WPT;
        u64 v[WPT];
        bool ok;
        do {
            ok = true;
            #pragma unroll
            for (int j = 0; j < WPT; ++j)
                v[j] = __hip_atomic_load(xs + j, __ATOMIC_RELAXED,
                                         __HIP_MEMORY_SCOPE_AGENT);
            #pragma unroll
            for (int j = 0; j < WPT; ++j)
                ok &= ((u32)(v[j] >> 32) == (u32)TSTEPS);
        } while (!ok);
        #pragma unroll
        for (int j = 0; j < WPT; ++j)
            xc[tid * WPT + j] = __uint_as_float((u32)v[j]);
        __syncthreads();

        float a = 0.0f;
        #pragma unroll
        for (int i = 0; i < WPT; ++i) a += wreg_out[i] * xc[tid + i * TPB];
        for (int off = 32; off; off >>= 1) a += __shfl_down(a, off, 64);
        if ((tid & 63) == 0) red[tid >> 6] = a;
        __syncthreads();
        if (tid == 0) {
            float s = 0.0f;
            #pragma unroll
            for (int i = 0; i < TPB / 64; ++i) s += red[i];
            Y[(size_t)(TSTEPS - 1) * NY + wg] = s;
        }
    }
}

extern "C" void kernel_launch(void* const* d_in, const int* in_sizes, int n_in,
                              void* d_out, int out_size, void* d_ws, size_t ws_size,
                              hipStream_t stream) {
    const float* UT   = (const float*)d_in[0];  // [T, NU]
    const float* x0   = (const float*)d_in[1];  // [NX]
    const float* Win  = (const float*)d_in[2];  // [NX, NU]
    const float* W    = (const float*)d_in[3];  // [NX, NX]
    const float* Wout = (const float*)d_in[4];  // [NY, NX]
    float* Y = (float*)d_out;                   // [T*NY]

    char* ws = (char*)d_ws;
    u64*  xbuf  = (u64*)ws;                     // 2*NX packed words = 64 KB
    u32*  flags = (u32*)(ws + 65536);           // 128 hint flags
    int*  rlen  = (int*)(ws + 69632);           // NX ints = 16 KB
    int2* ell   = (int2*)(ws + 86016);          // NX*CAP*8 = 11,534,336 B

    build_ell_kernel<<<dim3(NX), dim3(256), 0, stream>>>(W, ell, rlen, xbuf, flags);

    void* args[] = { (void*)&UT, (void*)&x0, (void*)&Win, (void*)&Wout,
                     (void*)&ell, (void*)&rlen, (void*)&xbuf, (void*)&flags,
                     (void*)&Y };
    hipLaunchCooperativeKernel((const void*)esn_kernel, dim3(WGS), dim3(TPB),
                               args, 0, stream);
}

// Round 6
// 21851.779 us; speedup vs baseline: 1.0577x; 1.0577x over previous
//
#include <hip/hip_runtime.h>
#include <math.h>

// ESN forward: x_{t+1} = 0.1*x_t + 0.9*tanh(W_in @ u_t + W @ x_t); y_t = Wout @ x_{t+1}
// R10 = R6's proven 64-WG exchange (hint flag -> ONE validated epoch-in-data
// round, fence-free, entries streamed from L2 in-loop) with the producer side
// re-granularized to WAVES:
//  - each consumer thread's 8 words = one 64B line = the 8 rows of exactly ONE
//    producer wave (flag index == consumer tid). After a wave's 8 row-stores,
//    a wave-local s_waitcnt vmcnt(0) orders them, lane 0 stores the wave flag.
//    -> barrier 2 deleted; detection gated by the earliest wave, not the
//    slowest WG. (Epoch validation still the only correctness gate.)
//  - variable-length round-robin gather (numerics proven in R7): avg ~13 int4s
//    vs 21 fixed; zero-padded tail contributes exactly 0.
//  - Y readout partials -> red[t&1][wave]; tid0 flushes prev step after the
//    (single) barrier. Fast exp2 tanh (R7-validated) on the publish path.
// Lessons kept: R7 (never drop the hint flag), R8 (entries live in L2, not
// LDS), R9 (64 WGs, not 128 - exchange cost scales with poll population).

#define NX 4096
#define NU 128
#define NY 64
#define TSTEPS 4096
#define CAP 352            // storage pad (mean nnz 204.8, sd 13.9)
#define WGS 64
#define TPB 512
#define RPW (NX / WGS)     // 64 rows per workgroup
#define UPT 16             // W_in floats per thread
#define WPT 8              // exchange words / readout floats per thread
#define NWV (TPB / 64)     // 8 waves per WG

typedef unsigned long long u64;
typedef unsigned int u32;

// --- Kernel 1: dense->ELL compaction + row lengths; zero xbuf + wave flags ---
__global__ void build_ell_kernel(const float* __restrict__ W, int2* __restrict__ ell,
                                 int* __restrict__ rlen, u64* __restrict__ xbuf,
                                 u32* __restrict__ flags) {
    const int r = blockIdx.x;
    const int tid = threadIdx.x;
    if (r == 0) { flags[tid] = 0; flags[tid + 256] = 0; }   // 512 wave flags
    if (r < 32) xbuf[r * 256 + tid] = 0;                    // 2*NX words
    const int wv = tid >> 6, ln = tid & 63;
    __shared__ int wave_tot[4];
    __shared__ int base;
    if (tid == 0) base = 0;
    __syncthreads();
    const float* row = W + (size_t)r * NX;
    int2* out = ell + (size_t)r * CAP;
    for (int chunk = 0; chunk < NX; chunk += 256) {
        float w = row[chunk + tid];
        bool p = (w != 0.0f);
        unsigned long long m = __ballot(p);
        int lp = (int)__popcll(m & ((1ull << ln) - 1ull));
        if (ln == 63) wave_tot[wv] = lp + (p ? 1 : 0);
        __syncthreads();
        int wbase = 0;
        #pragma unroll
        for (int i = 0; i < 4; ++i)
            if (i < wv) wbase += wave_tot[i];
        int tot = wave_tot[0] + wave_tot[1] + wave_tot[2] + wave_tot[3];
        if (p) {
            int o = base + wbase + lp;
            if (o < CAP) out[o] = make_int2(chunk + tid, __float_as_int(w));
        }
        __syncthreads();
        if (tid == 0) base += tot;
        __syncthreads();
    }
    // zero-pad remainder: col=0, val=0 contributes exactly 0
    for (int o = base + tid; o < CAP; o += 256) out[o] = make_int2(0, 0);
    if (tid == 0) rlen[r] = (base < CAP) ? base : CAP;
}

// --- Kernel 2: cooperative sequential recurrence, wave-granular publish ---
__global__ void __launch_bounds__(TPB, 1) esn_kernel(
    const float* __restrict__ UT, const float* __restrict__ x0,
    const float* __restrict__ Win, const float* __restrict__ Wout,
    const int2* __restrict__ ell, const int* __restrict__ rlen,
    u64* __restrict__ xbuf,   // [2][NX] packed (epoch<<32 | float bits)
    u32* __restrict__ flags,  // [WGS*NWV] wave flags, hint only
    float* __restrict__ Y)
{
    __shared__ __align__(16) float xl[2][NX];
    __shared__ float red[2][NWV];

    const int tid = threadIdx.x;
    const int wg  = blockIdx.x;              // 0..63
    const int grp = tid >> 3;                // row group within WG (0..63)
    const int ln  = tid & 7;                 // lane within row group
    const int wv  = tid >> 6;                // wave within WG (0..7)
    const int r   = wg * RPW + grp;          // global row this 8-thread group owns

    // varlen round-robin ELL view: lane ln consumes int4s {ln, ln+8, ln+16, ...}
    const int4* e4  = (const int4*)(ell + (size_t)r * CAP) + ln;
    const int   nit = (rlen[r] + 15) >> 4;   // int4s per lane (zero-padded tail)

    float4 wreg_in[UPT / 4];                 // Win[r, ln*16 .. +16) pinned
    {
        const float4* winrow = (const float4*)(Win + (size_t)r * NU + ln * UPT);
        #pragma unroll
        for (int i = 0; i < UPT / 4; ++i) wreg_in[i] = winrow[i];
    }
    float wreg_out[WPT];                     // Wout[wg, tid::512] pinned
    {
        const float* woutrow = Wout + (size_t)wg * NX;
        #pragma unroll
        for (int i = 0; i < WPT; ++i) wreg_out[i] = woutrow[tid + i * TPB];
    }

    for (int t = 0; t < TSTEPS; ++t) {
        float* xc = xl[t & 1];

        // ---- x-independent partial: acc = Win[r,:] @ u_t (before spin) ----
        float acc = 0.0f;
        {
            const float4* u4 = (const float4*)(UT + (size_t)t * NU + ln * UPT);
            #pragma unroll
            for (int i = 0; i < UPT / 4; ++i) {
                float4 u = u4[i];
                acc += wreg_in[i].x * u.x + wreg_in[i].y * u.y
                     + wreg_in[i].z * u.z + wreg_in[i].w * u.w;
            }
        }

        // ---- stage x_t into LDS: wave-flag hint, then validated data round ----
        if (t == 0) {
            const float4* xs4 = (const float4*)x0;
            float4* dst = (float4*)(xc + tid * WPT);
            dst[0] = xs4[2 * tid];
            dst[1] = xs4[2 * tid + 1];
        } else {
            // this thread's line is produced by wave (tid%8) of WG (tid/8):
            // flag index == tid. Hint only; epochs below are the gate.
            while (__hip_atomic_load(flags + tid, __ATOMIC_RELAXED,
                                     __HIP_MEMORY_SCOPE_AGENT) < (u32)t) { }
            const u64* xs = xbuf + (size_t)(t & 1) * NX + (size_t)tid * WPT;
            u64 v[WPT];
            bool ok;
            do {
                ok = true;
                #pragma unroll
                for (int j = 0; j < WPT; ++j)
                    v[j] = __hip_atomic_load(xs + j, __ATOMIC_RELAXED,
                                             __HIP_MEMORY_SCOPE_AGENT);
                #pragma unroll
                for (int j = 0; j < WPT; ++j)
                    ok &= ((u32)(v[j] >> 32) == (u32)t);
            } while (!ok);
            float4 lo = make_float4(__uint_as_float((u32)v[0]), __uint_as_float((u32)v[1]),
                                    __uint_as_float((u32)v[2]), __uint_as_float((u32)v[3]));
            float4 hi = make_float4(__uint_as_float((u32)v[4]), __uint_as_float((u32)v[5]),
                                    __uint_as_float((u32)v[6]), __uint_as_float((u32)v[7]));
            float4* dst = (float4*)(xc + tid * WPT);
            dst[0] = lo;
            dst[1] = hi;
        }
        __syncthreads();   // the ONLY barrier per step

        // ---- deferred Y flush: previous step's wave partials (barrier-ordered) ----
        if (tid == 0 && t >= 2) {
            float s = 0.0f;
            #pragma unroll
            for (int i = 0; i < NWV; ++i) s += red[(t - 1) & 1][i];
            Y[(size_t)(t - 2) * NY + wg] = s;
        }

        // ---- acc += W[r,:] @ x_t (varlen coalesced L2 stream, LDS x-gather) ----
        #pragma unroll 2
        for (int i = 0; i < nit; ++i) {
            int4 cv = e4[i << 3];
            acc += __int_as_float(cv.y) * xc[cv.x]
                 + __int_as_float(cv.w) * xc[cv.z];
        }
        acc += __shfl_down(acc, 4, 8);
        acc += __shfl_down(acc, 2, 8);
        acc += __shfl_down(acc, 1, 8);

        // ---- publish x_{t+1}: 8 row stores per wave, wave-local order, flag ----
        if (ln == 0) {
            float xold = xc[r];
            float a  = fminf(fmaxf(acc, -10.0f), 10.0f);
            float e  = exp2f(a * 2.885390081777927f);      // e^{2a}
            float th = (e - 1.0f) / (e + 1.0f);            // tanh(a)
            float xnew = __builtin_fmaf(0.9f, th, 0.1f * xold);
            u64 packed = ((u64)(u32)(t + 1) << 32) | (u64)__float_as_uint(xnew);
            __hip_atomic_store(xbuf + (size_t)((t + 1) & 1) * NX + r, packed,
                               __ATOMIC_RELAXED, __HIP_MEMORY_SCOPE_AGENT);
        }
        // wave-local: all this wave's row stores complete before its flag issues
        asm volatile("s_waitcnt vmcnt(0)" ::: "memory");
        if ((tid & 63) == 0)
            __hip_atomic_store(flags + wg * NWV + wv, (u32)(t + 1),
                               __ATOMIC_RELAXED, __HIP_MEMORY_SCOPE_AGENT);

        // ---- readout partials for y_{t-1} (off the critical path) ----
        if (t > 0) {
            float p = 0.0f;
            #pragma unroll
            for (int i = 0; i < WPT; ++i) p += wreg_out[i] * xc[tid + i * TPB];
            for (int off = 32; off; off >>= 1) p += __shfl_down(p, off, 64);
            if ((tid & 63) == 0) red[t & 1][wv] = p;
        }
    }

    // ---- final: stage x_T (epoch TSTEPS, buffer 0); flush Y[T-2], Y[T-1] ----
    {
        float* xc = xl[0];
        while (__hip_atomic_load(flags + tid, __ATOMIC_RELAXED,
                                 __HIP_MEMORY_SCOPE_AGENT) < (u32)TSTEPS) { }
        const u64* xs = xbuf + (size_t)(TSTEPS & 1) * NX + (size_t)tid * WPT;
        u64 v[WPT];
        bool ok;
        do {
            ok = true;
            #pragma unroll
            for (int j = 0; j < WPT; ++j)
                v[j] = __hip_atomic_load(xs + j, __ATOMIC_RELAXED,
                                         __HIP_MEMORY_SCOPE_AGENT);
            #pragma unroll
            for (int j = 0; j < WPT; ++j)
                ok &= ((u32)(v[j] >> 32) == (u32)TSTEPS);
        } while (!ok);
        #pragma unroll
        for (int j = 0; j < WPT; ++j)
            xc[tid * WPT + j] = __uint_as_float((u32)v[j]);
        __syncthreads();

        if (tid == 0) {
            float s = 0.0f;
            #pragma unroll
            for (int i = 0; i < NWV; ++i) s += red[(TSTEPS - 1) & 1][i];
            Y[(size_t)(TSTEPS - 2) * NY + wg] = s;
        }
        float p = 0.0f;
        #pragma unroll
        for (int i = 0; i < WPT; ++i) p += wreg_out[i] * xc[tid + i * TPB];
        for (int off = 32; off; off >>= 1) p += __shfl_down(p, off, 64);
        if ((tid & 63) == 0) red[0][wv] = p;
        __syncthreads();
        if (tid == 0) {
            float s = 0.0f;
            #pragma unroll
            for (int i = 0; i < NWV; ++i) s += red[0][i];
            Y[(size_t)(TSTEPS - 1) * NY + wg] = s;
        }
    }
}

extern "C" void kernel_launch(void* const* d_in, const int* in_sizes, int n_in,
                              void* d_out, int out_size, void* d_ws, size_t ws_size,
                              hipStream_t stream) {
    const float* UT   = (const float*)d_in[0];  // [T, NU]
    const float* x0   = (const float*)d_in[1];  // [NX]
    const float* Win  = (const float*)d_in[2];  // [NX, NU]
    const float* W    = (const float*)d_in[3];  // [NX, NX]
    const float* Wout = (const float*)d_in[4];  // [NY, NX]
    float* Y = (float*)d_out;                   // [T*NY]

    char* ws = (char*)d_ws;
    u64*  xbuf  = (u64*)ws;                     // 2*NX packed words = 64 KB
    u32*  flags = (u32*)(ws + 65536);           // 512 wave flags = 2 KB
    int*  rlen  = (int*)(ws + 69632);           // NX ints = 16 KB
    int2* ell   = (int2*)(ws + 86016);          // NX*CAP*8 = 11,534,336 B

    build_ell_kernel<<<dim3(NX), dim3(256), 0, stream>>>(W, ell, rlen, xbuf, flags);

    void* args[] = { (void*)&UT, (void*)&x0, (void*)&Win, (void*)&Wout,
                     (void*)&ell, (void*)&rlen, (void*)&xbuf, (void*)&flags,
                     (void*)&Y };
    hipLaunchCooperativeKernel((const void*)esn_kernel, dim3(WGS), dim3(TPB),
                               args, 0, stream);
}